// Round 4
// baseline (154.019 us; speedup 1.0000x reference)
//
#include <hip/hip_runtime.h>
#include <hip/hip_cooperative_groups.h>
#include <stdint.h>

namespace cg = cooperative_groups;

#define NUM_CLASSES 10
#define BOX_CODE 7
#define NUM_ANCHORS 4
#define HW 250000                    // 500*500
#define NQUAD (HW / 4)               // 62500 pixel-quads
#define NBUCKET 4096                 // 12-bit buckets
#define BSHIFT 20                    // key >> 20 -> bucket
#define CAP 4096                     // candidate cap (expected cnt ~2300)
#define BLK 256
#define GRID ((NQUAD + BLK - 1) / BLK)   // 245 blocks <= 256 CUs -> co-resident

__device__ __forceinline__ unsigned f2sort(float f) {
    unsigned b = __float_as_uint(f);
    // monotone float->uint mapping (bigger float -> bigger uint)
    return b ^ ((b & 0x80000000u) ? 0xFFFFFFFFu : 0x80000000u);
}

// One cooperative kernel: score+hist -> (gridsync) flush -> (gridsync)
// per-block threshold scan + register-compact -> (gridsync) rank-select+decode.
__global__ __launch_bounds__(BLK, 1)
void k_all(const float* __restrict__ cls, const float* __restrict__ bbox,
           const float* __restrict__ dirp, const float* __restrict__ anch,
           float* __restrict__ out,
           unsigned long long* __restrict__ cand,
           unsigned* __restrict__ hist,
           unsigned* __restrict__ mcount, int k)
{
    cg::grid_group grid = cg::this_grid();
    __shared__ unsigned long long shc[CAP];      // 32 KB; first 16 KB aliased as LDS hist
    unsigned* lh = (unsigned*)shc;
    __shared__ unsigned sT;
    const int tid  = threadIdx.x;
    const int gtid = blockIdx.x * BLK + tid;

    // ---------- Phase A: zero global hist/meta + LDS hist; compute 16 max-keys ----------
    for (int i = tid; i < NBUCKET; i += BLK) lh[i] = 0u;
    if (gtid < NBUCKET) atomicExch(&hist[gtid], 0u);   // blocks 0..15, coherent zero
    if (gtid == 0) atomicExch(mcount, 0u);
    __syncthreads();

    const bool act = (gtid < NQUAD);
    const int pix = gtid * 4;
    unsigned mk[NUM_ANCHORS][4];
    if (act) {
        float mx[NUM_ANCHORS][4];
#pragma unroll
        for (int a = 0; a < NUM_ANCHORS; ++a)
#pragma unroll
            for (int j = 0; j < 4; ++j) mx[a][j] = -INFINITY;
#pragma unroll
        for (int a = 0; a < NUM_ANCHORS; ++a) {
#pragma unroll
            for (int c = 0; c < NUM_CLASSES; ++c) {
                float4 v = *reinterpret_cast<const float4*>(
                    &cls[(size_t)(a * NUM_CLASSES + c) * HW + pix]);
                mx[a][0] = fmaxf(mx[a][0], v.x);
                mx[a][1] = fmaxf(mx[a][1], v.y);
                mx[a][2] = fmaxf(mx[a][2], v.z);
                mx[a][3] = fmaxf(mx[a][3], v.w);
            }
        }
#pragma unroll
        for (int a = 0; a < NUM_ANCHORS; ++a)
#pragma unroll
            for (int j = 0; j < 4; ++j) {
                mk[a][j] = f2sort(mx[a][j]);
                atomicAdd(&lh[mk[a][j] >> BSHIFT], 1u);
            }
    }
    grid.sync();   // s1: global hist zeroed everywhere; LDS hists complete

    // ---------- Phase B: flush LDS hist to global ----------
    for (int i = tid; i < NBUCKET; i += BLK) {
        unsigned v = lh[i];
        if (v) atomicAdd(&hist[i], v);
    }
    grid.sync();   // s2: hist final

    // ---------- Phase C1: per-block redundant threshold scan ----------
    unsigned ssum = 0;
    const int base = tid * (NBUCKET / BLK);      // 16 buckets per thread
#pragma unroll
    for (int j = 0; j < NBUCKET / BLK; ++j) ssum += hist[base + j];
    unsigned* arr = lh;                           // reuse LDS (phase-B reads done at s2)
    arr[tid] = ssum;
    __syncthreads();
    for (int off = 1; off < BLK; off <<= 1) {    // inclusive suffix scan
        unsigned v = (tid + off < BLK) ? arr[tid + off] : 0u;
        __syncthreads();
        arr[tid] += v;
        __syncthreads();
    }
    const unsigned incl = arr[tid];
    const unsigned excl = incl - ssum;
    if (excl < (unsigned)k && (unsigned)k <= incl) {  // exactly one thread/block
        unsigned acc = excl;
        for (int b = NBUCKET / BLK - 1; b >= 0; --b) {
            acc += hist[base + b];
            if (acc >= (unsigned)k) { sT = (unsigned)(base + b); break; }
        }
    }
    __syncthreads();
    const unsigned T = sT;

    // ---------- Phase C2: compact winners straight from registers ----------
    if (act) {
#pragma unroll
        for (int a = 0; a < NUM_ANCHORS; ++a)
#pragma unroll
            for (int j = 0; j < 4; ++j) {
                unsigned m = mk[a][j];
                if ((m >> BSHIFT) >= T) {
                    unsigned pos = atomicAdd(mcount, 1u);
                    if (pos < CAP) {
                        unsigned n = (unsigned)((pix + j) * NUM_ANCHORS + a);
                        // ascending key => descending score, ties ascending index
                        cand[pos] = ((unsigned long long)(m ^ 0xFFFFFFFFu) << 32) | n;
                    }
                }
            }
    }
    grid.sync();   // s3: cand + count final

    // ---------- Phase D: rank-select + decode + write ----------
    unsigned cnt = *mcount;
    if (cnt > CAP) cnt = CAP;
    if ((unsigned)(blockIdx.x * BLK) < cnt) {     // only blocks owning candidates
        for (unsigned i = tid; i < cnt; i += BLK) shc[i] = cand[i];
        __syncthreads();
        if ((unsigned)gtid < cnt) {
            const unsigned long long mykey = shc[gtid];
            unsigned rank = 0;
            for (unsigned m = 0; m < cnt; ++m)    // LDS broadcast scan
                rank += (shc[m] < mykey) ? 1u : 0u;
            if (rank < (unsigned)k) {
                const unsigned n = (unsigned)(mykey & 0xFFFFFFFFu);
                const unsigned p = n >> 2, a = n & 3u;
                // scores (sigmoid of the 10 class logits)
#pragma unroll
                for (int c = 0; c < NUM_CLASSES; ++c) {
                    float x = cls[(size_t)(a * NUM_CLASSES + c) * HW + p];
                    out[(size_t)rank * NUM_CLASSES + c] = 1.0f / (1.0f + expf(-x));
                }
                float d[BOX_CODE], A[BOX_CODE];
#pragma unroll
                for (int b = 0; b < BOX_CODE; ++b) {
                    d[b] = bbox[(size_t)(a * BOX_CODE + b) * HW + p];
                    A[b] = anch[(size_t)n * BOX_CODE + b];
                }
                // decode: anchors=(x,y,z,w,l,h,r), deltas=(xt,yt,zt,wt,lt,ht,rt)
                float za = A[2] + A[5] * 0.5f;
                float diag = sqrtf(A[4] * A[4] + A[3] * A[3]);
                float xg = d[0] * diag + A[0];
                float yg = d[1] * diag + A[1];
                float zg = d[2] * A[5] + za;
                float wg = expf(d[3]) * A[3];
                float lg = expf(d[4]) * A[4];
                float hg = expf(d[5]) * A[5];
                float rg = d[6] + A[6];
                zg -= hg * 0.5f;
                float* ob = out + (size_t)k * NUM_CLASSES + (size_t)rank * BOX_CODE;
                ob[0] = xg; ob[1] = yg; ob[2] = zg; ob[3] = wg;
                ob[4] = lg; ob[5] = hg; ob[6] = rg;
                // dir argmax (tie -> 0)
                float d0 = dirp[(size_t)(a * 2 + 0) * HW + p];
                float d1 = dirp[(size_t)(a * 2 + 1) * HW + p];
                out[(size_t)k * (NUM_CLASSES + BOX_CODE) + rank] = (d1 > d0) ? 1.0f : 0.0f;
            }
        }
    }
}

extern "C" void kernel_launch(void* const* d_in, const int* in_sizes, int n_in,
                              void* d_out, int out_size, void* d_ws, size_t ws_size,
                              hipStream_t stream) {
    const float* cls  = (const float*)d_in[0];
    const float* bbox = (const float*)d_in[1];
    const float* dirp = (const float*)d_in[2];
    const float* anch = (const float*)d_in[3];
    float* out = (float*)d_out;
    int k = out_size / (NUM_CLASSES + BOX_CODE + 1);   // 1000

    char* ws = (char*)d_ws;
    unsigned long long* cand = (unsigned long long*)ws;        // 32,768 B
    unsigned* hist   = (unsigned*)(ws + 32768);                // 16,384 B
    unsigned* mcount = (unsigned*)(ws + 32768 + 16384);        // 4 B

    void* args[] = {(void*)&cls, (void*)&bbox, (void*)&dirp, (void*)&anch,
                    (void*)&out, (void*)&cand, (void*)&hist, (void*)&mcount,
                    (void*)&k};
    hipLaunchCooperativeKernel(reinterpret_cast<void*>(k_all),
                               dim3(GRID), dim3(BLK), args, 0, stream);
}

// Round 5
// 120.409 us; speedup vs baseline: 1.2791x; 1.2791x over previous
//
#include <hip/hip_runtime.h>
#include <stdint.h>

#define NUM_CLASSES 10
#define BOX_CODE 7
#define NUM_ANCHORS 4
#define HW 250000                    // 500*500
#define NROWS (HW * NUM_ANCHORS)     // 1,000,000
#define NBUCKET 4096                 // 12-bit buckets
#define BSHIFT 20                    // key >> 20 -> bucket
#define CAP 4096                     // candidate cap (expected cnt ~2300)

__device__ __forceinline__ unsigned f2sort(float f) {
    unsigned b = __float_as_uint(f);
    // monotone float->uint mapping (bigger float -> bigger uint)
    return b ^ ((b & 0x80000000u) ? 0xFFFFFFFFu : 0x80000000u);
}

// Kernel 0: zero hist + count (tiny; in-graph this is ~launch overhead only)
__global__ __launch_bounds__(1024) void k_zero(unsigned* __restrict__ hist,
                                               unsigned* __restrict__ mcount) {
    int i = threadIdx.x;
#pragma unroll
    for (int j = i; j < NBUCKET; j += 1024) hist[j] = 0u;
    if (i == 0) *mcount = 0u;
}

// Kernel 1: per-pixel max logit per anchor -> sortable keys + LDS-privatized
// histogram. 1 pixel/thread, 977 blocks -> ~15 waves/CU (latency hiding).
__global__ __launch_bounds__(256) void k_score_hist(const float* __restrict__ cls,
                                                    unsigned* __restrict__ keys,
                                                    unsigned* __restrict__ hist) {
    __shared__ unsigned lh[NBUCKET];
    for (int i = threadIdx.x; i < NBUCKET; i += 256) lh[i] = 0u;
    __syncthreads();

    int p = blockIdx.x * 256 + threadIdx.x;
    if (p < HW) {
        float mx0 = -INFINITY, mx1 = -INFINITY, mx2 = -INFINITY, mx3 = -INFINITY;
#pragma unroll
        for (int c = 0; c < NUM_CLASSES; ++c) {
            mx0 = fmaxf(mx0, cls[(size_t)(0 * NUM_CLASSES + c) * HW + p]);
            mx1 = fmaxf(mx1, cls[(size_t)(1 * NUM_CLASSES + c) * HW + p]);
            mx2 = fmaxf(mx2, cls[(size_t)(2 * NUM_CLASSES + c) * HW + p]);
            mx3 = fmaxf(mx3, cls[(size_t)(3 * NUM_CLASSES + c) * HW + p]);
        }
        unsigned m0 = f2sort(mx0), m1 = f2sort(mx1), m2 = f2sort(mx2), m3 = f2sort(mx3);
        uint4 kv; kv.x = m0; kv.y = m1; kv.z = m2; kv.w = m3;
        *reinterpret_cast<uint4*>(&keys[(size_t)p * 4]) = kv;   // keys[n], n = p*4+a
        atomicAdd(&lh[m0 >> BSHIFT], 1u);
        atomicAdd(&lh[m1 >> BSHIFT], 1u);
        atomicAdd(&lh[m2 >> BSHIFT], 1u);
        atomicAdd(&lh[m3 >> BSHIFT], 1u);
    }
    __syncthreads();
    for (int i = threadIdx.x; i < NBUCKET; i += 256) {
        unsigned v = lh[i];
        if (v) atomicAdd(&hist[i], v);
    }
}

// Kernel 2: per-block redundant threshold scan (replaces serial 1-block k_scan),
// then compact candidates (bucket >= T) from the key array. 4 rows/thread.
__global__ __launch_bounds__(256) void k_compactT(const unsigned* __restrict__ keys,
                                                  const unsigned* __restrict__ hist,
                                                  unsigned long long* __restrict__ cand,
                                                  unsigned* __restrict__ mcount, int k) {
    __shared__ unsigned arr[256];
    __shared__ unsigned sT;
    const int tid = threadIdx.x;

    // --- threshold scan: 16 buckets per thread, kept in registers ---
    unsigned h[NBUCKET / 256];                    // 16
    const int base = tid * (NBUCKET / 256);
    unsigned ssum = 0;
#pragma unroll
    for (int j = 0; j < NBUCKET / 256; ++j) { h[j] = hist[base + j]; ssum += h[j]; }
    arr[tid] = ssum;
    __syncthreads();
    for (int off = 1; off < 256; off <<= 1) {     // inclusive suffix scan
        unsigned v = (tid + off < 256) ? arr[tid + off] : 0u;
        __syncthreads();
        arr[tid] += v;
        __syncthreads();
    }
    const unsigned incl = arr[tid];
    const unsigned excl = incl - ssum;
    if (excl < (unsigned)k && (unsigned)k <= incl) {   // exactly one thread
        unsigned acc = excl;
        for (int b = NBUCKET / 256 - 1; b >= 0; --b) {
            acc += h[b];
            if (acc >= (unsigned)k) { sT = (unsigned)(base + b); break; }
        }
    }
    __syncthreads();
    const unsigned T = sT;

    // --- compact ---
    int t = blockIdx.x * 256 + tid;
    if (t < NROWS / 4) {
        uint4 kv = *reinterpret_cast<const uint4*>(&keys[(size_t)t * 4]);
        unsigned m[4] = {kv.x, kv.y, kv.z, kv.w};
        int n0 = t * 4;
#pragma unroll
        for (int j = 0; j < 4; ++j) {
            if ((m[j] >> BSHIFT) >= T) {
                unsigned pos = atomicAdd(mcount, 1u);
                if (pos < CAP) {
                    // ascending key => descending score, ties ascending index
                    cand[pos] = ((unsigned long long)(m[j] ^ 0xFFFFFFFFu) << 32)
                                | (unsigned)(n0 + j);
                }
            }
        }
    }
}

// Kernel 3: single-block bitonic sort over next-pow2(count), then decode+write
// the top-k outputs directly from sorted keys.
__global__ __launch_bounds__(1024) void k_sortgather(const unsigned long long* __restrict__ cand,
                                                     const unsigned* __restrict__ mcount,
                                                     const float* __restrict__ cls,
                                                     const float* __restrict__ bbox,
                                                     const float* __restrict__ dirp,
                                                     const float* __restrict__ anch,
                                                     float* __restrict__ out, int k) {
    __shared__ unsigned long long key[CAP];
    const int tid = threadIdx.x;
    unsigned cnt = *mcount;
    if (cnt > CAP) cnt = CAP;
    unsigned n2 = 1024;                       // >= k
    while (n2 < cnt) n2 <<= 1;                // next pow2 >= cnt (<= CAP)
    for (unsigned i = tid; i < n2; i += 1024)
        key[i] = (i < cnt) ? cand[i] : 0xFFFFFFFFFFFFFFFFull;
    for (unsigned size = 2; size <= n2; size <<= 1) {
        for (unsigned stride = size >> 1; stride > 0; stride >>= 1) {
            __syncthreads();
            for (unsigned t = tid; t < n2 / 2; t += 1024) {
                unsigned lo = 2u * t - (t & (stride - 1u));
                unsigned hi = lo + stride;
                bool up = ((lo & size) == 0u);
                unsigned long long a = key[lo], b = key[hi];
                if ((a > b) == up) { key[lo] = b; key[hi] = a; }
            }
        }
    }
    __syncthreads();
    // decode + write: thread j owns output row j
    if (tid < k) {
        const unsigned n = (unsigned)(key[tid] & 0xFFFFFFFFu);
        const unsigned p = n >> 2, a = n & 3u;
#pragma unroll
        for (int c = 0; c < NUM_CLASSES; ++c) {
            float x = cls[(size_t)(a * NUM_CLASSES + c) * HW + p];
            out[(size_t)tid * NUM_CLASSES + c] = 1.0f / (1.0f + expf(-x));
        }
        float d[BOX_CODE], A[BOX_CODE];
#pragma unroll
        for (int b = 0; b < BOX_CODE; ++b) {
            d[b] = bbox[(size_t)(a * BOX_CODE + b) * HW + p];
            A[b] = anch[(size_t)n * BOX_CODE + b];
        }
        // decode: anchors=(x,y,z,w,l,h,r), deltas=(xt,yt,zt,wt,lt,ht,rt)
        float za = A[2] + A[5] * 0.5f;
        float diag = sqrtf(A[4] * A[4] + A[3] * A[3]);
        float xg = d[0] * diag + A[0];
        float yg = d[1] * diag + A[1];
        float zg = d[2] * A[5] + za;
        float wg = expf(d[3]) * A[3];
        float lg = expf(d[4]) * A[4];
        float hg = expf(d[5]) * A[5];
        float rg = d[6] + A[6];
        zg -= hg * 0.5f;
        float* ob = out + (size_t)k * NUM_CLASSES + (size_t)tid * BOX_CODE;
        ob[0] = xg; ob[1] = yg; ob[2] = zg; ob[3] = wg;
        ob[4] = lg; ob[5] = hg; ob[6] = rg;
        // dir argmax (tie -> 0)
        float d0 = dirp[(size_t)(a * 2 + 0) * HW + p];
        float d1 = dirp[(size_t)(a * 2 + 1) * HW + p];
        out[(size_t)k * (NUM_CLASSES + BOX_CODE) + tid] = (d1 > d0) ? 1.0f : 0.0f;
    }
}

extern "C" void kernel_launch(void* const* d_in, const int* in_sizes, int n_in,
                              void* d_out, int out_size, void* d_ws, size_t ws_size,
                              hipStream_t stream) {
    const float* cls  = (const float*)d_in[0];
    const float* bbox = (const float*)d_in[1];
    const float* dirp = (const float*)d_in[2];
    const float* anch = (const float*)d_in[3];
    float* out = (float*)d_out;
    const int k = out_size / (NUM_CLASSES + BOX_CODE + 1);   // 1000

    char* ws = (char*)d_ws;
    unsigned* keys   = (unsigned*)ws;                             // 4,000,000 B
    unsigned* hist   = (unsigned*)(ws + 4000000);                 // 16,384 B
    unsigned* mcount = (unsigned*)(ws + 4000000 + 16384);         // 4 B
    unsigned long long* cand = (unsigned long long*)(ws + 4016448); // 32,768 B

    k_zero<<<1, 1024, 0, stream>>>(hist, mcount);
    k_score_hist<<<(HW + 255) / 256, 256, 0, stream>>>(cls, keys, hist);
    k_compactT<<<(NROWS / 4 + 255) / 256, 256, 0, stream>>>(keys, hist, cand, mcount, k);
    k_sortgather<<<1, 1024, 0, stream>>>(cand, mcount, cls, bbox, dirp, anch, out, k);
}

// Round 6
// 97.798 us; speedup vs baseline: 1.5749x; 1.2312x over previous
//
#include <hip/hip_runtime.h>
#include <stdint.h>

#define NUM_CLASSES 10
#define BOX_CODE 7
#define NUM_ANCHORS 4
#define HW 250000                    // 500*500
#define NROWS (HW * NUM_ANCHORS)     // 1,000,000
#define NBUCKET 4096                 // 12-bit buckets
#define BSHIFT 20                    // key >> 20 -> bucket
#define CAP 4096                     // candidate cap (expected cnt ~1500)

__device__ __forceinline__ unsigned f2sort(float f) {
    unsigned b = __float_as_uint(f);
    // monotone float->uint mapping (bigger float -> bigger uint)
    return b ^ ((b & 0x80000000u) ? 0xFFFFFFFFu : 0x80000000u);
}

// Kernel 0: zero hist + count (tiny; in-graph this is ~launch overhead only)
__global__ __launch_bounds__(1024) void k_zero(unsigned* __restrict__ hist,
                                               unsigned* __restrict__ mcount) {
    int i = threadIdx.x;
#pragma unroll
    for (int j = i; j < NBUCKET; j += 1024) hist[j] = 0u;
    if (i == 0) *mcount = 0u;
}

// Kernel 1: per-pixel max logit per anchor -> sortable keys + LDS-privatized
// histogram. 1 pixel/thread, 977 blocks.
__global__ __launch_bounds__(256) void k_score_hist(const float* __restrict__ cls,
                                                    unsigned* __restrict__ keys,
                                                    unsigned* __restrict__ hist) {
    __shared__ unsigned lh[NBUCKET];
    for (int i = threadIdx.x; i < NBUCKET; i += 256) lh[i] = 0u;
    __syncthreads();

    int p = blockIdx.x * 256 + threadIdx.x;
    if (p < HW) {
        float mx0 = -INFINITY, mx1 = -INFINITY, mx2 = -INFINITY, mx3 = -INFINITY;
#pragma unroll
        for (int c = 0; c < NUM_CLASSES; ++c) {
            mx0 = fmaxf(mx0, cls[(size_t)(0 * NUM_CLASSES + c) * HW + p]);
            mx1 = fmaxf(mx1, cls[(size_t)(1 * NUM_CLASSES + c) * HW + p]);
            mx2 = fmaxf(mx2, cls[(size_t)(2 * NUM_CLASSES + c) * HW + p]);
            mx3 = fmaxf(mx3, cls[(size_t)(3 * NUM_CLASSES + c) * HW + p]);
        }
        unsigned m0 = f2sort(mx0), m1 = f2sort(mx1), m2 = f2sort(mx2), m3 = f2sort(mx3);
        uint4 kv; kv.x = m0; kv.y = m1; kv.z = m2; kv.w = m3;
        *reinterpret_cast<uint4*>(&keys[(size_t)p * 4]) = kv;   // keys[n], n = p*4+a
        atomicAdd(&lh[m0 >> BSHIFT], 1u);
        atomicAdd(&lh[m1 >> BSHIFT], 1u);
        atomicAdd(&lh[m2 >> BSHIFT], 1u);
        atomicAdd(&lh[m3 >> BSHIFT], 1u);
    }
    __syncthreads();
    for (int i = threadIdx.x; i < NBUCKET; i += 256) {
        unsigned v = lh[i];
        if (v) atomicAdd(&hist[i], v);
    }
}

// Kernel 2: per-block redundant threshold scan, then compact candidates
// (bucket >= T) from the key array. 4 rows/thread.
__global__ __launch_bounds__(256) void k_compactT(const unsigned* __restrict__ keys,
                                                  const unsigned* __restrict__ hist,
                                                  unsigned long long* __restrict__ cand,
                                                  unsigned* __restrict__ mcount, int k) {
    __shared__ unsigned arr[256];
    __shared__ unsigned sT;
    const int tid = threadIdx.x;

    // --- threshold scan: 16 buckets per thread, kept in registers ---
    unsigned h[NBUCKET / 256];                    // 16
    const int base = tid * (NBUCKET / 256);
    unsigned ssum = 0;
#pragma unroll
    for (int j = 0; j < NBUCKET / 256; ++j) { h[j] = hist[base + j]; ssum += h[j]; }
    arr[tid] = ssum;
    __syncthreads();
    for (int off = 1; off < 256; off <<= 1) {     // inclusive suffix scan
        unsigned v = (tid + off < 256) ? arr[tid + off] : 0u;
        __syncthreads();
        arr[tid] += v;
        __syncthreads();
    }
    const unsigned incl = arr[tid];
    const unsigned excl = incl - ssum;
    if (excl < (unsigned)k && (unsigned)k <= incl) {   // exactly one thread
        unsigned acc = excl;
        for (int b = NBUCKET / 256 - 1; b >= 0; --b) {
            acc += h[b];
            if (acc >= (unsigned)k) { sT = (unsigned)(base + b); break; }
        }
    }
    __syncthreads();
    const unsigned T = sT;

    // --- compact ---
    int t = blockIdx.x * 256 + tid;
    if (t < NROWS / 4) {
        uint4 kv = *reinterpret_cast<const uint4*>(&keys[(size_t)t * 4]);
        unsigned m[4] = {kv.x, kv.y, kv.z, kv.w};
        int n0 = t * 4;
#pragma unroll
        for (int j = 0; j < 4; ++j) {
            if ((m[j] >> BSHIFT) >= T) {
                unsigned pos = atomicAdd(mcount, 1u);
                if (pos < CAP) {
                    // ascending key => descending score, ties ascending index
                    cand[pos] = ((unsigned long long)(m[j] ^ 0xFFFFFFFFu) << 32)
                                | (unsigned)(n0 + j);
                }
            }
        }
    }
}

// Kernel 3: parallel exact rank-selection + decode + write.
// Keys are unique (score||index), so rank = #{keys < mine} is each candidate's
// exact output position. 64 blocks x 64 threads = 4096 threads cover CAP.
__global__ __launch_bounds__(64) void k_rankgather(const unsigned long long* __restrict__ cand,
                                                   const unsigned* __restrict__ mcount,
                                                   const float* __restrict__ cls,
                                                   const float* __restrict__ bbox,
                                                   const float* __restrict__ dirp,
                                                   const float* __restrict__ anch,
                                                   float* __restrict__ out, int k) {
    __shared__ unsigned long long shc[CAP];       // 32 KB
    unsigned cnt = *mcount;
    if (cnt > CAP) cnt = CAP;
    const unsigned tid = threadIdx.x;
    const unsigned gtid = blockIdx.x * 64u + tid;
    if (blockIdx.x * 64u >= cnt) return;          // block owns no candidates

    for (unsigned i = tid; i < cnt; i += 64u) shc[i] = cand[i];
    __syncthreads();

    if (gtid >= cnt) return;
    const unsigned long long mykey = shc[gtid];
    unsigned rank = 0;
    unsigned m = 0;
#pragma unroll 4
    for (; m + 4 <= cnt; m += 4) {
        rank += (shc[m + 0] < mykey) ? 1u : 0u;
        rank += (shc[m + 1] < mykey) ? 1u : 0u;
        rank += (shc[m + 2] < mykey) ? 1u : 0u;
        rank += (shc[m + 3] < mykey) ? 1u : 0u;
    }
    for (; m < cnt; ++m) rank += (shc[m] < mykey) ? 1u : 0u;
    if (rank >= (unsigned)k) return;

    const unsigned n = (unsigned)(mykey & 0xFFFFFFFFu);
    const unsigned p = n >> 2, a = n & 3u;
#pragma unroll
    for (int c = 0; c < NUM_CLASSES; ++c) {
        float x = cls[(size_t)(a * NUM_CLASSES + c) * HW + p];
        out[(size_t)rank * NUM_CLASSES + c] = 1.0f / (1.0f + expf(-x));
    }
    float d[BOX_CODE], A[BOX_CODE];
#pragma unroll
    for (int b = 0; b < BOX_CODE; ++b) {
        d[b] = bbox[(size_t)(a * BOX_CODE + b) * HW + p];
        A[b] = anch[(size_t)n * BOX_CODE + b];
    }
    // decode: anchors=(x,y,z,w,l,h,r), deltas=(xt,yt,zt,wt,lt,ht,rt)
    float za = A[2] + A[5] * 0.5f;
    float diag = sqrtf(A[4] * A[4] + A[3] * A[3]);
    float xg = d[0] * diag + A[0];
    float yg = d[1] * diag + A[1];
    float zg = d[2] * A[5] + za;
    float wg = expf(d[3]) * A[3];
    float lg = expf(d[4]) * A[4];
    float hg = expf(d[5]) * A[5];
    float rg = d[6] + A[6];
    zg -= hg * 0.5f;
    float* ob = out + (size_t)k * NUM_CLASSES + (size_t)rank * BOX_CODE;
    ob[0] = xg; ob[1] = yg; ob[2] = zg; ob[3] = wg;
    ob[4] = lg; ob[5] = hg; ob[6] = rg;
    // dir argmax (tie -> 0)
    float d0 = dirp[(size_t)(a * 2 + 0) * HW + p];
    float d1 = dirp[(size_t)(a * 2 + 1) * HW + p];
    out[(size_t)k * (NUM_CLASSES + BOX_CODE) + rank] = (d1 > d0) ? 1.0f : 0.0f;
}

extern "C" void kernel_launch(void* const* d_in, const int* in_sizes, int n_in,
                              void* d_out, int out_size, void* d_ws, size_t ws_size,
                              hipStream_t stream) {
    const float* cls  = (const float*)d_in[0];
    const float* bbox = (const float*)d_in[1];
    const float* dirp = (const float*)d_in[2];
    const float* anch = (const float*)d_in[3];
    float* out = (float*)d_out;
    const int k = out_size / (NUM_CLASSES + BOX_CODE + 1);   // 1000

    char* ws = (char*)d_ws;
    unsigned* keys   = (unsigned*)ws;                             // 4,000,000 B
    unsigned* hist   = (unsigned*)(ws + 4000000);                 // 16,384 B
    unsigned* mcount = (unsigned*)(ws + 4000000 + 16384);         // 4 B
    unsigned long long* cand = (unsigned long long*)(ws + 4016448); // 32,768 B

    k_zero<<<1, 1024, 0, stream>>>(hist, mcount);
    k_score_hist<<<(HW + 255) / 256, 256, 0, stream>>>(cls, keys, hist);
    k_compactT<<<(NROWS / 4 + 255) / 256, 256, 0, stream>>>(keys, hist, cand, mcount, k);
    k_rankgather<<<CAP / 64, 64, 0, stream>>>(cand, mcount, cls, bbox, dirp, anch, out, k);
}

// Round 7
// 91.485 us; speedup vs baseline: 1.6835x; 1.0690x over previous
//
#include <hip/hip_runtime.h>
#include <stdint.h>

#define NUM_CLASSES 10
#define BOX_CODE 7
#define NUM_ANCHORS 4
#define HW 250000                    // 500*500
#define NROWS (HW * NUM_ANCHORS)     // 1,000,000
#define NBUCKET 4096                 // 12-bit buckets
#define BSHIFT 20                    // key >> 20 -> bucket
#define CAP 4096                     // candidate cap (measured cnt ~2650)

__device__ __forceinline__ unsigned f2sort(float f) {
    unsigned b = __float_as_uint(f);
    // monotone float->uint mapping (bigger float -> bigger uint)
    return b ^ ((b & 0x80000000u) ? 0xFFFFFFFFu : 0x80000000u);
}

// Kernel 0: zero hist + count (tiny; in-graph this is ~launch overhead only)
__global__ __launch_bounds__(1024) void k_zero(unsigned* __restrict__ hist,
                                               unsigned* __restrict__ mcount) {
    int i = threadIdx.x;
#pragma unroll
    for (int j = i; j < NBUCKET; j += 1024) hist[j] = 0u;
    if (i == 0) *mcount = 0u;
}

// Kernel 1: 4 pixels/thread, float4 channel loads -> sortable keys +
// LDS-privatized histogram. 245 blocks, 40 in-flight 1KB loads per wave.
__global__ __launch_bounds__(256) void k_score_hist(const float* __restrict__ cls,
                                                    unsigned* __restrict__ keys,
                                                    unsigned* __restrict__ hist) {
    __shared__ unsigned lh[NBUCKET];
    for (int i = threadIdx.x; i < NBUCKET; i += 256) lh[i] = 0u;
    __syncthreads();

    int t = blockIdx.x * 256 + threadIdx.x;      // 0 .. HW/4-1
    if (t < HW / 4) {
        int pix = t * 4;
        float mx[NUM_ANCHORS][4];
#pragma unroll
        for (int a = 0; a < NUM_ANCHORS; ++a)
#pragma unroll
            for (int j = 0; j < 4; ++j) mx[a][j] = -INFINITY;
#pragma unroll
        for (int a = 0; a < NUM_ANCHORS; ++a) {
#pragma unroll
            for (int c = 0; c < NUM_CLASSES; ++c) {
                float4 v = *reinterpret_cast<const float4*>(
                    &cls[(size_t)(a * NUM_CLASSES + c) * HW + pix]);
                mx[a][0] = fmaxf(mx[a][0], v.x);
                mx[a][1] = fmaxf(mx[a][1], v.y);
                mx[a][2] = fmaxf(mx[a][2], v.z);
                mx[a][3] = fmaxf(mx[a][3], v.w);
            }
        }
#pragma unroll
        for (int j = 0; j < 4; ++j) {
            unsigned m0 = f2sort(mx[0][j]);
            unsigned m1 = f2sort(mx[1][j]);
            unsigned m2 = f2sort(mx[2][j]);
            unsigned m3 = f2sort(mx[3][j]);
            uint4 kv; kv.x = m0; kv.y = m1; kv.z = m2; kv.w = m3;
            *reinterpret_cast<uint4*>(&keys[(size_t)(pix + j) * 4]) = kv;
            atomicAdd(&lh[m0 >> BSHIFT], 1u);
            atomicAdd(&lh[m1 >> BSHIFT], 1u);
            atomicAdd(&lh[m2 >> BSHIFT], 1u);
            atomicAdd(&lh[m3 >> BSHIFT], 1u);
        }
    }
    __syncthreads();
    for (int i = threadIdx.x; i < NBUCKET; i += 256) {
        unsigned v = lh[i];
        if (v) atomicAdd(&hist[i], v);
    }
}

// Kernel 2: per-block redundant threshold scan, then compact candidates
// (bucket >= T) from the key array. 4 rows/thread.
__global__ __launch_bounds__(256) void k_compactT(const unsigned* __restrict__ keys,
                                                  const unsigned* __restrict__ hist,
                                                  unsigned long long* __restrict__ cand,
                                                  unsigned* __restrict__ mcount, int k) {
    __shared__ unsigned arr[256];
    __shared__ unsigned sT;
    const int tid = threadIdx.x;

    // --- threshold scan: 16 buckets per thread, kept in registers ---
    unsigned h[NBUCKET / 256];                    // 16
    const int base = tid * (NBUCKET / 256);
    unsigned ssum = 0;
#pragma unroll
    for (int j = 0; j < NBUCKET / 256; ++j) { h[j] = hist[base + j]; ssum += h[j]; }
    arr[tid] = ssum;
    __syncthreads();
    for (int off = 1; off < 256; off <<= 1) {     // inclusive suffix scan
        unsigned v = (tid + off < 256) ? arr[tid + off] : 0u;
        __syncthreads();
        arr[tid] += v;
        __syncthreads();
    }
    const unsigned incl = arr[tid];
    const unsigned excl = incl - ssum;
    if (excl < (unsigned)k && (unsigned)k <= incl) {   // exactly one thread
        unsigned acc = excl;
        for (int b = NBUCKET / 256 - 1; b >= 0; --b) {
            acc += h[b];
            if (acc >= (unsigned)k) { sT = (unsigned)(base + b); break; }
        }
    }
    __syncthreads();
    const unsigned T = sT;

    // --- compact ---
    int t = blockIdx.x * 256 + tid;
    if (t < NROWS / 4) {
        uint4 kv = *reinterpret_cast<const uint4*>(&keys[(size_t)t * 4]);
        unsigned m[4] = {kv.x, kv.y, kv.z, kv.w};
        int n0 = t * 4;
#pragma unroll
        for (int j = 0; j < 4; ++j) {
            if ((m[j] >> BSHIFT) >= T) {
                unsigned pos = atomicAdd(mcount, 1u);
                if (pos < CAP) {
                    // ascending key => descending score, ties ascending index
                    cand[pos] = ((unsigned long long)(m[j] ^ 0xFFFFFFFFu) << 32)
                                | (unsigned)(n0 + j);
                }
            }
        }
    }
}

// Kernel 3: parallel exact rank-selection + decode + write.
// Keys are unique (score||index), so rank = #{keys < mine} is each candidate's
// exact output position. 16 blocks x 256 threads (4 waves/block for latency
// hiding) cover CAP candidates.
__global__ __launch_bounds__(256) void k_rankgather(const unsigned long long* __restrict__ cand,
                                                    const unsigned* __restrict__ mcount,
                                                    const float* __restrict__ cls,
                                                    const float* __restrict__ bbox,
                                                    const float* __restrict__ dirp,
                                                    const float* __restrict__ anch,
                                                    float* __restrict__ out, int k) {
    __shared__ unsigned long long shc[CAP];       // 32 KB
    unsigned cnt = *mcount;
    if (cnt > CAP) cnt = CAP;
    const unsigned tid = threadIdx.x;
    const unsigned gtid = blockIdx.x * 256u + tid;
    if (blockIdx.x * 256u >= cnt) return;         // block owns no candidates

    for (unsigned i = tid; i < cnt; i += 256u) shc[i] = cand[i];
    __syncthreads();

    if (gtid >= cnt) return;
    const unsigned long long mykey = shc[gtid];
    unsigned rank = 0;
    unsigned m = 0;
    for (; m + 8 <= cnt; m += 8) {
        rank += (shc[m + 0] < mykey) ? 1u : 0u;
        rank += (shc[m + 1] < mykey) ? 1u : 0u;
        rank += (shc[m + 2] < mykey) ? 1u : 0u;
        rank += (shc[m + 3] < mykey) ? 1u : 0u;
        rank += (shc[m + 4] < mykey) ? 1u : 0u;
        rank += (shc[m + 5] < mykey) ? 1u : 0u;
        rank += (shc[m + 6] < mykey) ? 1u : 0u;
        rank += (shc[m + 7] < mykey) ? 1u : 0u;
    }
    for (; m < cnt; ++m) rank += (shc[m] < mykey) ? 1u : 0u;
    if (rank >= (unsigned)k) return;

    const unsigned n = (unsigned)(mykey & 0xFFFFFFFFu);
    const unsigned p = n >> 2, a = n & 3u;
#pragma unroll
    for (int c = 0; c < NUM_CLASSES; ++c) {
        float x = cls[(size_t)(a * NUM_CLASSES + c) * HW + p];
        out[(size_t)rank * NUM_CLASSES + c] = 1.0f / (1.0f + expf(-x));
    }
    float d[BOX_CODE], A[BOX_CODE];
#pragma unroll
    for (int b = 0; b < BOX_CODE; ++b) {
        d[b] = bbox[(size_t)(a * BOX_CODE + b) * HW + p];
        A[b] = anch[(size_t)n * BOX_CODE + b];
    }
    // decode: anchors=(x,y,z,w,l,h,r), deltas=(xt,yt,zt,wt,lt,ht,rt)
    float za = A[2] + A[5] * 0.5f;
    float diag = sqrtf(A[4] * A[4] + A[3] * A[3]);
    float xg = d[0] * diag + A[0];
    float yg = d[1] * diag + A[1];
    float zg = d[2] * A[5] + za;
    float wg = expf(d[3]) * A[3];
    float lg = expf(d[4]) * A[4];
    float hg = expf(d[5]) * A[5];
    float rg = d[6] + A[6];
    zg -= hg * 0.5f;
    float* ob = out + (size_t)k * NUM_CLASSES + (size_t)rank * BOX_CODE;
    ob[0] = xg; ob[1] = yg; ob[2] = zg; ob[3] = wg;
    ob[4] = lg; ob[5] = hg; ob[6] = rg;
    // dir argmax (tie -> 0)
    float d0 = dirp[(size_t)(a * 2 + 0) * HW + p];
    float d1 = dirp[(size_t)(a * 2 + 1) * HW + p];
    out[(size_t)k * (NUM_CLASSES + BOX_CODE) + rank] = (d1 > d0) ? 1.0f : 0.0f;
}

extern "C" void kernel_launch(void* const* d_in, const int* in_sizes, int n_in,
                              void* d_out, int out_size, void* d_ws, size_t ws_size,
                              hipStream_t stream) {
    const float* cls  = (const float*)d_in[0];
    const float* bbox = (const float*)d_in[1];
    const float* dirp = (const float*)d_in[2];
    const float* anch = (const float*)d_in[3];
    float* out = (float*)d_out;
    const int k = out_size / (NUM_CLASSES + BOX_CODE + 1);   // 1000

    char* ws = (char*)d_ws;
    unsigned* keys   = (unsigned*)ws;                             // 4,000,000 B
    unsigned* hist   = (unsigned*)(ws + 4000000);                 // 16,384 B
    unsigned* mcount = (unsigned*)(ws + 4000000 + 16384);         // 4 B
    unsigned long long* cand = (unsigned long long*)(ws + 4016448); // 32,768 B

    k_zero<<<1, 1024, 0, stream>>>(hist, mcount);
    k_score_hist<<<(HW / 4 + 255) / 256, 256, 0, stream>>>(cls, keys, hist);
    k_compactT<<<(NROWS / 4 + 255) / 256, 256, 0, stream>>>(keys, hist, cand, mcount, k);
    k_rankgather<<<CAP / 256, 256, 0, stream>>>(cand, mcount, cls, bbox, dirp, anch, out, k);
}

// Round 8
// 62.019 us; speedup vs baseline: 2.4834x; 1.4751x over previous
//
#include <hip/hip_runtime.h>
#include <stdint.h>

#define NUM_CLASSES 10
#define BOX_CODE 7
#define NUM_ANCHORS 4
#define HW 250000                    // 500*500
#define NROWS (HW * NUM_ANCHORS)     // 1,000,000
#define NBUCKET 4096                 // 12-bit buckets
#define BSHIFT 20                    // key >> 20 -> bucket
#define CAP 4096                     // candidate cap (measured cnt ~2650)
#define CHUNK 256                    // rank-partial tile

__device__ __forceinline__ unsigned f2sort(float f) {
    unsigned b = __float_as_uint(f);
    // monotone float->uint mapping (bigger float -> bigger uint)
    return b ^ ((b & 0x80000000u) ? 0xFFFFFFFFu : 0x80000000u);
}

// Kernel 0: zero hist + grank + count
__global__ __launch_bounds__(1024) void k_zero(unsigned* __restrict__ hist,
                                               unsigned* __restrict__ grank,
                                               unsigned* __restrict__ mcount) {
    int i = threadIdx.x;
#pragma unroll
    for (int j = i; j < NBUCKET; j += 1024) hist[j] = 0u;
#pragma unroll
    for (int j = i; j < CAP; j += 1024) grank[j] = 0u;
    if (i == 0) *mcount = 0u;
}

// Kernel 1: 4 pixels/thread, float4 channel loads -> sortable keys +
// LDS-privatized histogram.
__global__ __launch_bounds__(256) void k_score_hist(const float* __restrict__ cls,
                                                    unsigned* __restrict__ keys,
                                                    unsigned* __restrict__ hist) {
    __shared__ unsigned lh[NBUCKET];
    for (int i = threadIdx.x; i < NBUCKET; i += 256) lh[i] = 0u;
    __syncthreads();

    int t = blockIdx.x * 256 + threadIdx.x;      // 0 .. HW/4-1
    if (t < HW / 4) {
        int pix = t * 4;
        float mx[NUM_ANCHORS][4];
#pragma unroll
        for (int a = 0; a < NUM_ANCHORS; ++a)
#pragma unroll
            for (int j = 0; j < 4; ++j) mx[a][j] = -INFINITY;
#pragma unroll
        for (int a = 0; a < NUM_ANCHORS; ++a) {
#pragma unroll
            for (int c = 0; c < NUM_CLASSES; ++c) {
                float4 v = *reinterpret_cast<const float4*>(
                    &cls[(size_t)(a * NUM_CLASSES + c) * HW + pix]);
                mx[a][0] = fmaxf(mx[a][0], v.x);
                mx[a][1] = fmaxf(mx[a][1], v.y);
                mx[a][2] = fmaxf(mx[a][2], v.z);
                mx[a][3] = fmaxf(mx[a][3], v.w);
            }
        }
#pragma unroll
        for (int j = 0; j < 4; ++j) {
            unsigned m0 = f2sort(mx[0][j]);
            unsigned m1 = f2sort(mx[1][j]);
            unsigned m2 = f2sort(mx[2][j]);
            unsigned m3 = f2sort(mx[3][j]);
            uint4 kv; kv.x = m0; kv.y = m1; kv.z = m2; kv.w = m3;
            *reinterpret_cast<uint4*>(&keys[(size_t)(pix + j) * 4]) = kv;
            atomicAdd(&lh[m0 >> BSHIFT], 1u);
            atomicAdd(&lh[m1 >> BSHIFT], 1u);
            atomicAdd(&lh[m2 >> BSHIFT], 1u);
            atomicAdd(&lh[m3 >> BSHIFT], 1u);
        }
    }
    __syncthreads();
    for (int i = threadIdx.x; i < NBUCKET; i += 256) {
        unsigned v = lh[i];
        if (v) atomicAdd(&hist[i], v);
    }
}

// Kernel 2: per-block redundant threshold scan, then compact candidates
// (bucket >= T) from the key array. 4 rows/thread.
__global__ __launch_bounds__(256) void k_compactT(const unsigned* __restrict__ keys,
                                                  const unsigned* __restrict__ hist,
                                                  unsigned long long* __restrict__ cand,
                                                  unsigned* __restrict__ mcount, int k) {
    __shared__ unsigned arr[256];
    __shared__ unsigned sT;
    const int tid = threadIdx.x;

    // --- threshold scan: 16 buckets per thread, kept in registers ---
    unsigned h[NBUCKET / 256];                    // 16
    const int base = tid * (NBUCKET / 256);
    unsigned ssum = 0;
#pragma unroll
    for (int j = 0; j < NBUCKET / 256; ++j) { h[j] = hist[base + j]; ssum += h[j]; }
    arr[tid] = ssum;
    __syncthreads();
    for (int off = 1; off < 256; off <<= 1) {     // inclusive suffix scan
        unsigned v = (tid + off < 256) ? arr[tid + off] : 0u;
        __syncthreads();
        arr[tid] += v;
        __syncthreads();
    }
    const unsigned incl = arr[tid];
    const unsigned excl = incl - ssum;
    if (excl < (unsigned)k && (unsigned)k <= incl) {   // exactly one thread
        unsigned acc = excl;
        for (int b = NBUCKET / 256 - 1; b >= 0; --b) {
            acc += h[b];
            if (acc >= (unsigned)k) { sT = (unsigned)(base + b); break; }
        }
    }
    __syncthreads();
    const unsigned T = sT;

    // --- compact ---
    int t = blockIdx.x * 256 + tid;
    if (t < NROWS / 4) {
        uint4 kv = *reinterpret_cast<const uint4*>(&keys[(size_t)t * 4]);
        unsigned m[4] = {kv.x, kv.y, kv.z, kv.w};
        int n0 = t * 4;
#pragma unroll
        for (int j = 0; j < 4; ++j) {
            if ((m[j] >> BSHIFT) >= T) {
                unsigned pos = atomicAdd(mcount, 1u);
                if (pos < CAP) {
                    // ascending key => descending score, ties ascending index
                    cand[pos] = ((unsigned long long)(m[j] ^ 0xFFFFFFFFu) << 32)
                                | (unsigned)(n0 + j);
                }
            }
        }
    }
}

// Kernel 3: distributed partial rank. Block (ci,cj): candidates ci*256+tid
// vs key chunk cj (staged in LDS). Keys unique -> rank = #{keys < mine}.
// ~121 active blocks spread over CUs; 16 atomicAdds per rank counter.
__global__ __launch_bounds__(256) void k_rankpart(const unsigned long long* __restrict__ cand,
                                                  const unsigned* __restrict__ mcount,
                                                  unsigned* __restrict__ grank) {
    __shared__ unsigned long long shk[CHUNK];     // 2 KB
    unsigned cnt = *mcount;
    if (cnt > CAP) cnt = CAP;
    const unsigned ci = blockIdx.x, cj = blockIdx.y;
    if (ci * CHUNK >= cnt || cj * CHUNK >= cnt) return;
    const unsigned tid = threadIdx.x;

    unsigned j = cj * CHUNK + tid;
    shk[tid] = (j < cnt) ? cand[j] : 0xFFFFFFFFFFFFFFFFull;  // pad never counts
    __syncthreads();

    const unsigned gi = ci * CHUNK + tid;
    if (gi >= cnt) return;
    const unsigned long long mykey = cand[gi];
    unsigned r = 0;
#pragma unroll 8
    for (int m = 0; m < CHUNK; ++m)
        r += (shk[m] < mykey) ? 1u : 0u;
    if (r) atomicAdd(&grank[gi], r);
}

// Kernel 4: gather + decode + write for candidates with rank < k.
__global__ __launch_bounds__(256) void k_gatherdecode(const unsigned long long* __restrict__ cand,
                                                      const unsigned* __restrict__ mcount,
                                                      const unsigned* __restrict__ grank,
                                                      const float* __restrict__ cls,
                                                      const float* __restrict__ bbox,
                                                      const float* __restrict__ dirp,
                                                      const float* __restrict__ anch,
                                                      float* __restrict__ out, int k) {
    unsigned cnt = *mcount;
    if (cnt > CAP) cnt = CAP;
    const unsigned gtid = blockIdx.x * 256u + threadIdx.x;
    if (gtid >= cnt) return;
    const unsigned rank = grank[gtid];
    if (rank >= (unsigned)k) return;

    const unsigned n = (unsigned)(cand[gtid] & 0xFFFFFFFFu);
    const unsigned p = n >> 2, a = n & 3u;
#pragma unroll
    for (int c = 0; c < NUM_CLASSES; ++c) {
        float x = cls[(size_t)(a * NUM_CLASSES + c) * HW + p];
        out[(size_t)rank * NUM_CLASSES + c] = 1.0f / (1.0f + expf(-x));
    }
    float d[BOX_CODE], A[BOX_CODE];
#pragma unroll
    for (int b = 0; b < BOX_CODE; ++b) {
        d[b] = bbox[(size_t)(a * BOX_CODE + b) * HW + p];
        A[b] = anch[(size_t)n * BOX_CODE + b];
    }
    // decode: anchors=(x,y,z,w,l,h,r), deltas=(xt,yt,zt,wt,lt,ht,rt)
    float za = A[2] + A[5] * 0.5f;
    float diag = sqrtf(A[4] * A[4] + A[3] * A[3]);
    float xg = d[0] * diag + A[0];
    float yg = d[1] * diag + A[1];
    float zg = d[2] * A[5] + za;
    float wg = expf(d[3]) * A[3];
    float lg = expf(d[4]) * A[4];
    float hg = expf(d[5]) * A[5];
    float rg = d[6] + A[6];
    zg -= hg * 0.5f;
    float* ob = out + (size_t)k * NUM_CLASSES + (size_t)rank * BOX_CODE;
    ob[0] = xg; ob[1] = yg; ob[2] = zg; ob[3] = wg;
    ob[4] = lg; ob[5] = hg; ob[6] = rg;
    // dir argmax (tie -> 0)
    float d0 = dirp[(size_t)(a * 2 + 0) * HW + p];
    float d1 = dirp[(size_t)(a * 2 + 1) * HW + p];
    out[(size_t)k * (NUM_CLASSES + BOX_CODE) + rank] = (d1 > d0) ? 1.0f : 0.0f;
}

extern "C" void kernel_launch(void* const* d_in, const int* in_sizes, int n_in,
                              void* d_out, int out_size, void* d_ws, size_t ws_size,
                              hipStream_t stream) {
    const float* cls  = (const float*)d_in[0];
    const float* bbox = (const float*)d_in[1];
    const float* dirp = (const float*)d_in[2];
    const float* anch = (const float*)d_in[3];
    float* out = (float*)d_out;
    const int k = out_size / (NUM_CLASSES + BOX_CODE + 1);   // 1000

    char* ws = (char*)d_ws;
    unsigned* keys   = (unsigned*)ws;                               // 4,000,000 B
    unsigned* hist   = (unsigned*)(ws + 4000000);                   // 16,384 B
    unsigned* mcount = (unsigned*)(ws + 4016384);                   // 4 B (pad to 64)
    unsigned* grank  = (unsigned*)(ws + 4016448);                   // 16,384 B
    unsigned long long* cand = (unsigned long long*)(ws + 4032832); // 32,768 B

    k_zero<<<1, 1024, 0, stream>>>(hist, grank, mcount);
    k_score_hist<<<(HW / 4 + 255) / 256, 256, 0, stream>>>(cls, keys, hist);
    k_compactT<<<(NROWS / 4 + 255) / 256, 256, 0, stream>>>(keys, hist, cand, mcount, k);
    k_rankpart<<<dim3(CAP / CHUNK, CAP / CHUNK), 256, 0, stream>>>(cand, mcount, grank);
    k_gatherdecode<<<CAP / 256, 256, 0, stream>>>(cand, mcount, grank, cls, bbox, dirp, anch, out, k);
}